// Round 15
// baseline (25.883 us; speedup 1.0000x reference)
//
#include <hip/hip_runtime.h>
#include <math.h>

// B=64, C=3, H=W=256 fixed by the reference problem.
#define BATCH 64
#define CH 3
#define IMH 256
#define IMW 256
#define HW (IMH * IMW)
#define NXCD 8

// 32x256 FULL-HEIGHT band, one channel per block (1536 blocks).
// No vertical tile overlap: staged rows = all 256 (rlo=0, NR=256 always).
// Col bound: px = lx-axlo <= 34 (proof: floor(sxlo+31c) <= floor(sxlo)+31,
// axlo >= lxmin-3) -> XW=36 words, sampled words 0..35.
#define XW 36
#define XW4 9              // float4 per staged row
#define NQ (IMH * XW4)     // 2304 quads = 36 KB; == 9 * 256 EXACTLY:
#define NIT 9              // zero padding, zero waste, no clamp divergence
// LDS 36 KB -> 4 blocks/CU.

#define AS1 __attribute__((address_space(1)))
#define AS3 __attribute__((address_space(3)))

__device__ __forceinline__ int clampi(int v, int lo, int hi) {
    return min(max(v, lo), hi);
}

__global__ __launch_bounds__(256, 4) void TCR_52536039964687_warp(
    const float* __restrict__ img,
    const float* __restrict__ rnd,
    float* __restrict__ out) {
    __shared__ float4 lds4[NQ];
    float* lds = (float*)lds4;

    // 1536 blocks = 64 images x 8 bands x 3 channels.
    // XCD-affinity: all 24 blocks of image b land on XCD b%8
    // (assumes HW round-robin xcd = bid % 8; perf-only assumption).
    int w = blockIdx.x;
    int xcd = w & (NXCD - 1);
    unsigned t = (unsigned)w >> 3;   // 0..191 within XCD
    unsigned islot = t / 24u;        // image slot within XCD, 0..7
    unsigned rem = t - islot * 24u;  // 0..23
    int b = ((int)islot << 3) | xcd; // image index
    int ch = (int)(rem >> 3);        // channel 0..2
    int band = (int)(rem & 7u);
    int X0 = band << 5;              // band col origin (32-wide)

    int tid = threadIdx.x;
    int cg = tid & 7;                // col group: 4 consecutive cols
    int qy = tid >> 3;               // 0..31; rows qy + 32*rr, rr<8

    // ---- per-image inverse affine coefficients (simplified; a==0 exactly) ----
    const float r = rnd[b];
    const float ANG  = 0.34906585039886590f;   // deg2rad(20)
    const float ANG2 = 0.69813170079773179f;   // 2*ANG
    const float Wc = (float)IMH;
    const float Hc = (float)IMW;

    float tx  = 12.0f * r - 6.0f;
    float ty  = tx;
    float rho = ANG2 * r - ANG;

    float s = __sinf(rho);
    float c = __cosf(rho);            // 0.9397 <= c <= 1.0
    float cb = 2.f * c * c - 1.f;     // cos(2*rho) >= 0.766
    float sb = 2.f * s * c;           // sin(2*rho)
    float rcb = 1.f / cb;

    float ic  = 0.5f * Wc * (1.f - c) - tx;
    float id_ = -sb * c * rcb;        // |id_| <= 0.7885
    float ie  = c * rcb;              // 1.0 <= ie <= 1.2267
    float P   = 0.5f * (Wc * c - Wc + 2.f * tx);
    float Q   = 0.5f * (Hc * c - Wc * cb + 2.f * ty * cb - Wc * sb + 2.f * tx * sb);
    float if_ = (sb * P - Q) * rcb;
    // sx = fmaf(c, x, ic); sy = fmaf(id_, x, fmaf(ie, y, if_))

    // ---- band x-origin for staging (sx independent of y) ----
    float sxlo = fmaf(c, (float)X0, ic);           // min sx over band (c>0)
    int lxmin = clampi((int)floorf(sxlo), 0, IMW - 2);
    int axlo = lxmin & ~3;            // 16B-aligned staging origin

    const float* cbase = img + (size_t)b * CH * HW + ch * HW;

    // ---- STAGE: 9 always-issued global_load_lds per thread (2304 quads =
    //      exactly all 256 rows x 9 quads). Dest index e LINEAR (HW writes
    //      wave base + lane*16). Source: row e/9, col quad axlo+4q clamped
    //      to 252; clamp only fires for intended cols > 255, whose words
    //      are never sampled (sampled word <= px+1, col <= 255, and axlo
    //      4-aligned puts col 255 in the unclamped quad base 252).
    #pragma unroll
    for (int it = 0; it < NIT; ++it) {
        int e = tid + it * 256;
        unsigned row = (unsigned)e / XW4;         // 0..255 (magic mul)
        int q = e - (int)row * XW4;               // 0..8
        int gq = min(axlo + 4 * q, IMW - 4);
        const float* gp = cbase + (int)row * IMW + gq;
        __builtin_amdgcn_global_load_lds((const AS1 void*)gp,
                                         (AS3 void*)&lds4[e], 16, 0, 0);
    }

    // ---- per-thread x taps: 4 columns (computed under stage latency) ----
    float wl[4], wh[4];
    int   px[4];
    float fxj[4];
    #pragma unroll
    for (int j = 0; j < 4; ++j) {
        float fx = (float)(X0 + cg * 4 + j);
        fxj[j] = fx;
        float sx = fmaf(c, fx, ic);
        float x0f = floorf(sx);
        int x0 = (int)x0f;
        float wx = sx - x0f;
        int lx = clampi(x0, 0, IMW - 2);  // lx >= lxmin >= axlo (monotone)
        wl[j] = (x0 == lx) ? (1.f - wx) : ((x0 == lx - 1) ? wx : 0.f);
        wh[j] = (x0 == lx) ? wx : ((x0 == lx + 1) ? (1.f - wx) : 0.f);
        px[j] = lx - axlo;                // 0..34
    }

    __syncthreads();      // drains vmcnt -> staged LDS visible

    // output base: 16B-aligned (X0 mult of 32, cg*4 mult of 4 floats)
    float* obase = out + (size_t)b * CH * HW + ch * HW + qy * IMW + X0 + cg * 4;

    // ---- sample: 8 row-groups x 4 cols; y-taps inline (used once) ----
    #pragma unroll
    for (int rr = 0; rr < 8; ++rr) {
        float fy = (float)(qy + 32 * rr);
        float g = fmaf(ie, fy, if_);
        float4 v;
        #pragma unroll
        for (int j = 0; j < 4; ++j) {
            float sy = fmaf(id_, fxj[j], g);
            float y0f = floorf(sy);
            int y0 = (int)y0f;
            int y1 = y0 + 1;
            float wy = sy - y0f;
            float wy0 = ((y0 >= 0) & (y0 < IMH)) ? (1.f - wy) : 0.f;
            float wy1 = ((y1 >= 0) & (y1 < IMH)) ? wy : 0.f;
            int a0 = clampi(y0, 0, IMH - 1) * XW + px[j];   // <= 9214
            int a1 = clampi(y1, 0, IMH - 1) * XW + px[j];
            float l00 = lds[a0], l01 = lds[a0 + 1];   // ds_read2_b32
            float l10 = lds[a1], l11 = lds[a1 + 1];
            ((float*)&v)[j] = (l00 * wl[j] + l01 * wh[j]) * wy0
                            + (l10 * wl[j] + l11 * wh[j]) * wy1;
        }
        *(float4*)(obase + rr * 32 * IMW) = v;
    }
}

extern "C" void kernel_launch(void* const* d_in, const int* in_sizes, int n_in,
                              void* d_out, int out_size, void* d_ws, size_t ws_size,
                              hipStream_t stream) {
    const float* img = (const float*)d_in[0];
    const float* rnd = (const float*)d_in[1];
    float* out = (float*)d_out;
    (void)d_ws; (void)ws_size;

    hipLaunchKernelGGL(TCR_52536039964687_warp, dim3(BATCH * 8 * CH), dim3(256),
                       0, stream, img, rnd, out);
}